// Round 1
// 1180.796 us; speedup vs baseline: 1.1527x; 1.1527x over previous
//
#include <hip/hip_runtime.h>
#include <math.h>

// 2-layer LSTM (B=1024,T=512,F=64,H=128) + FC head.
// R6: same layer-pipelined producer/consumer structure as R5 (blocks 0-63 =
// layer0, 64-127 = layer1, flag publish every 8 steps, light barriers), but
// the 8x-replicated per-wave A-operand work is now COOPERATIVE:
//  - producer: each thread loads 2 floats of the 16x64 x-tile, does a cheap
//    truncation hi/lo bf16 split (~10 instrs vs ~170 replicated per wave),
//    stages into a double-buffered LDS x-pool; waves read A-frags via
//    ds_read_b128 (same pattern as hbuf).
//  - consumer: each thread loads 8B of the 16x128 h1-tile from global and
//    stages into LDS (was 64B/lane replicated across all 8 waves).
//  - h1c relaid out as [t][B][H]: per-step addressing is one pointer
//    increment; stores use base + 256B immediate offsets; step working set
//    is one contiguous 256KB slab.

#define BB 1024
#define TT 512
#define FF 64
#define HH 128

typedef __attribute__((ext_vector_type(8))) short     v8s;  // 8 x bf16
typedef __attribute__((ext_vector_type(8))) _Float16  v8h;  // 8 x fp16
typedef __attribute__((ext_vector_type(4))) float     v4f;

__device__ __forceinline__ float sigmoidf_(float x) {
    return 1.0f / (1.0f + __expf(-x));
}
__device__ __forceinline__ float tanhf_(float x) {
    return 1.0f - 2.0f / (1.0f + __expf(2.0f * x));
}
__device__ __forceinline__ short bf16r(float v) {  // RNE fp32->bf16
    unsigned u = __float_as_uint(v);
    return (short)((u + 0x7FFFu + ((u >> 16) & 1u)) >> 16);
}
__device__ __forceinline__ float bf16tof(short s) {
    return __uint_as_float(((unsigned)(unsigned short)s) << 16);
}
// Barrier WITHOUT the compiler's vmcnt(0) drain (LDS ordering only).
__device__ __forceinline__ void light_barrier() {
    asm volatile("s_waitcnt lgkmcnt(0)\n\ts_barrier" ::: "memory");
}
// Bounded acquire-poll on a device-scope flag (RMW -> always coherent).
__device__ __forceinline__ void wait_flag_ge(int* f, int need) {
    for (int i = 0; i < 2000000; ++i) {
        int v = __hip_atomic_fetch_add(f, 0, __ATOMIC_ACQUIRE,
                                       __HIP_MEMORY_SCOPE_AGENT);
        if (v >= need) return;
        __builtin_amdgcn_s_sleep(4);
    }
}
// Truncation-based hi/lo bf16 split of two floats, packed into 2 u32
// (lo16 = elem a, hi16 = elem b). hi is exact top-16-bits; remainder is
// exact in fp32; lo truncated -> x represented to ~2^-16 relative.
__device__ __forceinline__ void split2(float a, float b,
                                       unsigned& hi, unsigned& lo) {
    unsigned ua = __float_as_uint(a), ub = __float_as_uint(b);
    hi = (ua >> 16) | (ub & 0xFFFF0000u);
    float ra = a - __uint_as_float(ua & 0xFFFF0000u);
    float rb = b - __uint_as_float(ub & 0xFFFF0000u);
    lo = (__float_as_uint(ra) >> 16) | (__float_as_uint(rb) & 0xFFFF0000u);
}

// MFMA 16x16x32 layouts: A/B: m(n)=lane&15, k=(lane>>4)*8+j ; C/D: col=lane&15,
// row=(lane>>4)*4+r.

__global__ __launch_bounds__(512, 2) void fused_lstm_kernel(
    const float* __restrict__ x,
    const float* __restrict__ Wih0, const float* __restrict__ Whh0,
    const float* __restrict__ bih0, const float* __restrict__ bhh0,
    const float* __restrict__ Wih1, const float* __restrict__ Whh1,
    const float* __restrict__ bih1, const float* __restrict__ bhh1,
    _Float16* __restrict__ h1c, float* __restrict__ hs, int* __restrict__ flags)
{
    const int tid = threadIdx.x;
    const int w = tid >> 6;
    const int l = tid & 63;
    const int lane16 = l & 15;
    const int quad = l >> 4;
    const int jh = 16 * w + lane16;

    __shared__ _Float16 hbuf[2][16 * 136];      // 8704 B
    __shared__ short    xpool[2][2][16 * 72];   // 9216 B; consumer reuses as sbuf

    if (blockIdx.x < 64) {
        // ================= LAYER 0 (producer) =================
        const int tile = blockIdx.x;
        const long b0 = (long)tile * 16;
        int* flagp = &flags[tile];

        v8h bh[4][4];                 // Whh0 fp16 B-frags
        v8s bxh[4][2], bxl[4][2];     // Wih0 split-bf16 B-frags
        float bias[4];
        float c[4] = {0.f, 0.f, 0.f, 0.f};

#pragma unroll
        for (int g = 0; g < 4; ++g) {
            const int col = g * 128 + jh;
            bias[g] = bih0[col] + bhh0[col];
#pragma unroll
            for (int q = 0; q < 4; ++q) {
                const float* p = &Whh0[(long)col * HH + q * 32 + quad * 8];
                float4 u0 = *(const float4*)p;
                float4 u1 = *(const float4*)(p + 4);
                v8h t;
                t[0]=(_Float16)u0.x; t[1]=(_Float16)u0.y; t[2]=(_Float16)u0.z; t[3]=(_Float16)u0.w;
                t[4]=(_Float16)u1.x; t[5]=(_Float16)u1.y; t[6]=(_Float16)u1.z; t[7]=(_Float16)u1.w;
                bh[g][q] = t;
            }
#pragma unroll
            for (int q = 0; q < 2; ++q) {
                const float* p = &Wih0[(long)col * FF + q * 32 + quad * 8];
                float4 u0 = *(const float4*)p;
                float4 u1 = *(const float4*)(p + 4);
                float vv[8] = {u0.x,u0.y,u0.z,u0.w,u1.x,u1.y,u1.z,u1.w};
                v8s hi, lo;
#pragma unroll
                for (int e = 0; e < 8; ++e) {
                    short hbits = bf16r(vv[e]);
                    hi[e] = hbits;
                    lo[e] = bf16r(vv[e] - bf16tof(hbits));
                }
                bxh[g][q] = hi; bxl[g][q] = lo;
            }
        }

        for (int i = tid; i < 16 * 136; i += 512) hbuf[0][i] = (_Float16)0.0f;

        // ---- cooperative x staging: thread owns 2 floats of the 16x64 tile
        const int xr_row = tid >> 5;          // 0..15 (batch row within tile)
        const int xr_col = (tid & 31) * 2;    // 0..62, even
        const float* xp = &x[(b0 + xr_row) * TT * FF + xr_col];
        {   // xpool[0] = x(t=0)
            float2 x0 = *(const float2*)xp;
            unsigned hi, lo; split2(x0.x, x0.y, hi, lo);
            *(unsigned*)&xpool[0][0][xr_row * 72 + xr_col] = hi;
            *(unsigned*)&xpool[0][1][xr_row * 72 + xr_col] = lo;
        }
        float2 xreg = *(const float2*)(xp + FF);   // x(t=1)
        xp += 2 * FF;                              // points at t=2
        __syncthreads();

        _Float16* h1p = h1c + (b0 + quad * 4) * HH + jh;   // [t][B][H]

        for (int t = 0; t < TT; ++t) {
            const int cur = t & 1, nxt = cur ^ 1;

            // A-frags from LDS (shared across all 8 waves)
            v8s xh[2], xl[2];
#pragma unroll
            for (int q = 0; q < 2; ++q) {
                xh[q] = *(const v8s*)&xpool[cur][0][lane16 * 72 + q * 32 + quad * 8];
                xl[q] = *(const v8s*)&xpool[cur][1][lane16 * 72 + q * 32 + quad * 8];
            }
            v8h ah[4];
#pragma unroll
            for (int q = 0; q < 4; ++q)
                ah[q] = *(const v8h*)&hbuf[cur][lane16 * 136 + q * 32 + quad * 8];

            // stage x(t+1) into xpool[nxt]; prefetch x(t+2)
            {
                unsigned hi, lo; split2(xreg.x, xreg.y, hi, lo);
                *(unsigned*)&xpool[nxt][0][xr_row * 72 + xr_col] = hi;
                *(unsigned*)&xpool[nxt][1][xr_row * 72 + xr_col] = lo;
            }
            xreg = *(const float2*)xp;
            if (t < TT - 3) xp += FF;

            v4f acc[4];
#pragma unroll
            for (int g = 0; g < 4; ++g) {
                v4f a = {bias[g], bias[g], bias[g], bias[g]};
                a = __builtin_amdgcn_mfma_f32_16x16x32_bf16(xh[0], bxh[g][0], a, 0, 0, 0);
                a = __builtin_amdgcn_mfma_f32_16x16x32_bf16(xh[0], bxl[g][0], a, 0, 0, 0);
                a = __builtin_amdgcn_mfma_f32_16x16x32_bf16(xl[0], bxh[g][0], a, 0, 0, 0);
                a = __builtin_amdgcn_mfma_f32_16x16x32_bf16(xh[1], bxh[g][1], a, 0, 0, 0);
                a = __builtin_amdgcn_mfma_f32_16x16x32_bf16(xh[1], bxl[g][1], a, 0, 0, 0);
                a = __builtin_amdgcn_mfma_f32_16x16x32_bf16(xl[1], bxh[g][1], a, 0, 0, 0);
#pragma unroll
                for (int q = 0; q < 4; ++q)
                    a = __builtin_amdgcn_mfma_f32_16x16x32_f16(ah[q], bh[g][q], a, 0, 0, 0);
                acc[g] = a;
            }

#pragma unroll
            for (int r = 0; r < 4; ++r) {
                float ig = sigmoidf_(acc[0][r]);
                float fg = sigmoidf_(acc[1][r]);
                float gg = tanhf_(acc[2][r]);
                float og = sigmoidf_(acc[3][r]);
                c[r] = fmaf(fg, c[r], ig * gg);
                float h = og * tanhf_(c[r]);
                const int m = quad * 4 + r;
                const _Float16 hh = (_Float16)h;
                h1p[r * HH] = hh;
                hbuf[nxt][m * 136 + jh] = hh;
            }
            h1p += (long)BB * HH;

            if ((t & 7) == 7) {
                __syncthreads();  // drains every wave's h1c stores (vmcnt 0)
                if (tid == 0)
                    __hip_atomic_store(flagp, t + 1, __ATOMIC_RELEASE,
                                       __HIP_MEMORY_SCOPE_AGENT);
            } else {
                light_barrier();
            }
        }
    } else {
        // ================= LAYER 1 (consumer) =================
        const int tile = blockIdx.x - 64;
        const long b0 = (long)tile * 16;
        int* flagp = &flags[tile];

        v8h bi[4][4], bh[4][4];
        float bias[4];
        float c[4] = {0.f, 0.f, 0.f, 0.f};

#pragma unroll
        for (int g = 0; g < 4; ++g) {
            const int col = g * 128 + jh;
            bias[g] = bih1[col] + bhh1[col];
#pragma unroll
            for (int q = 0; q < 4; ++q) {
                const float* pi = &Wih1[(long)col * HH + q * 32 + quad * 8];
                float4 u0 = *(const float4*)pi;
                float4 u1 = *(const float4*)(pi + 4);
                v8h t;
                t[0]=(_Float16)u0.x; t[1]=(_Float16)u0.y; t[2]=(_Float16)u0.z; t[3]=(_Float16)u0.w;
                t[4]=(_Float16)u1.x; t[5]=(_Float16)u1.y; t[6]=(_Float16)u1.z; t[7]=(_Float16)u1.w;
                bi[g][q] = t;
                const float* ph = &Whh1[(long)col * HH + q * 32 + quad * 8];
                float4 v0 = *(const float4*)ph;
                float4 v1 = *(const float4*)(ph + 4);
                v8h s;
                s[0]=(_Float16)v0.x; s[1]=(_Float16)v0.y; s[2]=(_Float16)v0.z; s[3]=(_Float16)v0.w;
                s[4]=(_Float16)v1.x; s[5]=(_Float16)v1.y; s[6]=(_Float16)v1.z; s[7]=(_Float16)v1.w;
                bh[g][q] = s;
            }
        }

        for (int i = tid; i < 16 * 136; i += 512) hbuf[0][i] = (_Float16)0.0f;

        _Float16* sb = (_Float16*)xpool;      // [2][16*136] staging for h1

        const int hr_row = tid >> 5;          // 0..15
        const int hr_col = (tid & 31) * 4;    // 0..124, multiple of 4

        // wait for h1[0..15] before the t=0 staging (covers prefetch window)
        if (tid == 0) wait_flag_ge(flagp, 16);
        __syncthreads();

        const _Float16* hp0 = h1c + (b0 + hr_row) * HH + hr_col;  // t=0
        {
            uint2 h0v = *(const uint2*)hp0;
            *(uint2*)&sb[0 * 2176 + hr_row * 136 + hr_col] = h0v;
        }
        uint2 hreg = *(const uint2*)(hp0 + (long)BB * HH);        // h1(t=1)
        const _Float16* hpp = hp0 + 2L * BB * HH;                 // points at t=2
        __syncthreads();

        for (int t = 0; t < TT; ++t) {
            if ((t & 7) == 0 && t > 0) {
                if (tid == 0) wait_flag_ge(flagp, (t + 16 < TT) ? t + 16 : TT);
                light_barrier();
            }
            const int cur = t & 1, nxt = cur ^ 1;

            v8h a1[4], a2[4];
#pragma unroll
            for (int q = 0; q < 4; ++q) {
                a1[q] = *(const v8h*)&sb[cur * 2176 + lane16 * 136 + q * 32 + quad * 8];
                a2[q] = *(const v8h*)&hbuf[cur][lane16 * 136 + q * 32 + quad * 8];
            }

            // stage h1(t+1) into sb[nxt]; prefetch h1(t+2)
            *(uint2*)&sb[nxt * 2176 + hr_row * 136 + hr_col] = hreg;
            hreg = *(const uint2*)hpp;
            if (t < TT - 3) hpp += (long)BB * HH;

            v4f acc[4];
#pragma unroll
            for (int g = 0; g < 4; ++g) {
                v4f a = {bias[g], bias[g], bias[g], bias[g]};
#pragma unroll
                for (int q = 0; q < 4; ++q)
                    a = __builtin_amdgcn_mfma_f32_16x16x32_f16(a1[q], bi[g][q], a, 0, 0, 0);
#pragma unroll
                for (int q = 0; q < 4; ++q)
                    a = __builtin_amdgcn_mfma_f32_16x16x32_f16(a2[q], bh[g][q], a, 0, 0, 0);
                acc[g] = a;
            }

#pragma unroll
            for (int r = 0; r < 4; ++r) {
                float ig = sigmoidf_(acc[0][r]);
                float fg = sigmoidf_(acc[1][r]);
                float gg = tanhf_(acc[2][r]);
                float og = sigmoidf_(acc[3][r]);
                c[r] = fmaf(fg, c[r], ig * gg);
                float h = og * tanhf_(c[r]);
                const int m = quad * 4 + r;
                hbuf[nxt][m * 136 + jh] = (_Float16)h;
                if (t == TT - 1) hs[(b0 + m) * HH + jh] = h;
            }
            light_barrier();
        }
    }
}

// ---------------- FC head: out = relu(h @ fc1^T + b1) @ fc2^T + b2 ----------
__global__ __launch_bounds__(64) void head_kernel(
    const float* __restrict__ h, const float* __restrict__ w1,
    const float* __restrict__ b1, const float* __restrict__ w2,
    const float* __restrict__ b2, float* __restrict__ out)
{
    const int b = blockIdx.x;
    const int n = threadIdx.x;
    float acc = b1[n];
#pragma unroll
    for (int k = 0; k < HH; ++k)
        acc = fmaf(w1[n * HH + k], h[b * HH + k], acc);
    float v = fmaxf(acc, 0.0f) * w2[n];
#pragma unroll
    for (int off = 32; off > 0; off >>= 1)
        v += __shfl_down(v, off);
    if (n == 0) out[b] = v + b2[0];
}

extern "C" void kernel_launch(void* const* d_in, const int* in_sizes, int n_in,
                              void* d_out, int out_size, void* d_ws, size_t ws_size,
                              hipStream_t stream)
{
    const float* x    = (const float*)d_in[0];
    const float* Wih0 = (const float*)d_in[1];
    const float* Whh0 = (const float*)d_in[2];
    const float* bih0 = (const float*)d_in[3];
    const float* bhh0 = (const float*)d_in[4];
    const float* Wih1 = (const float*)d_in[5];
    const float* Whh1 = (const float*)d_in[6];
    const float* bih1 = (const float*)d_in[7];
    const float* bhh1 = (const float*)d_in[8];
    const float* w1   = (const float*)d_in[9];
    const float* b1   = (const float*)d_in[10];
    const float* w2   = (const float*)d_in[11];
    const float* b2   = (const float*)d_in[12];
    float* out = (float*)d_out;

    char* ws = (char*)d_ws;
    _Float16* h1c = (_Float16*)ws;                              // 134 MB, [t][B][H]
    float* hs  = (float*)(ws + (size_t)BB * TT * HH * sizeof(_Float16));
    int* flags = (int*)(ws + (size_t)BB * TT * HH * sizeof(_Float16)
                           + (size_t)BB * HH * sizeof(float));

    hipMemsetAsync(flags, 0, 64 * sizeof(int), stream);

    fused_lstm_kernel<<<128, 512, 0, stream>>>(
        x, Wih0, Whh0, bih0, bhh0, Wih1, Whh1, bih1, bhh1, h1c, hs, flags);
    head_kernel<<<BB, 64, 0, stream>>>(hs, w1, b1, w2, b2, out);
}

// Round 2
// 1136.325 us; speedup vs baseline: 1.1978x; 1.0391x over previous
//
#include <hip/hip_runtime.h>
#include <math.h>

// 2-layer LSTM (B=1024,T=512,F=64,H=128) + FC head.
// R7: R6 structure (layer-pipelined producer/consumer, cooperative LDS
// staging, [t][B][H] h1c) + ONE-STEP SOFTWARE PIPELINE of the
// recurrence-independent MFMA work:
//  - producer: xacc(t+1) = bias + Wih0*x(t+1) (24 MFMAs) is computed during
//    step t from a triple-buffered x-pool; step t's critical path is only
//    {barrier -> ds_read ah -> 16 h-MFMAs (4-deep chains) -> gates -> write}.
//  - consumer: a1acc(t+1) = bias + Wih1*h1(t+1) (16 MFMAs) likewise
//    precomputed from triple-buffered h1 staging slots.
//  - accumulation order unchanged (bias -> x-part -> h-part) => numerics
//    identical to R6.
//  - __launch_bounds__(512,1): grid=128 on 256 CUs -> 1 block/CU anyway;
//    gives register headroom for the pipelined accumulators.

#define BB 1024
#define TT 512
#define FF 64
#define HH 128

typedef __attribute__((ext_vector_type(8))) short     v8s;  // 8 x bf16
typedef __attribute__((ext_vector_type(8))) _Float16  v8h;  // 8 x fp16
typedef __attribute__((ext_vector_type(4))) float     v4f;

__device__ __forceinline__ float sigmoidf_(float x) {
    return 1.0f / (1.0f + __expf(-x));
}
__device__ __forceinline__ float tanhf_(float x) {
    return 1.0f - 2.0f / (1.0f + __expf(2.0f * x));
}
__device__ __forceinline__ short bf16r(float v) {  // RNE fp32->bf16
    unsigned u = __float_as_uint(v);
    return (short)((u + 0x7FFFu + ((u >> 16) & 1u)) >> 16);
}
__device__ __forceinline__ float bf16tof(short s) {
    return __uint_as_float(((unsigned)(unsigned short)s) << 16);
}
// Barrier WITHOUT the compiler's vmcnt(0) drain (LDS ordering only).
__device__ __forceinline__ void light_barrier() {
    asm volatile("s_waitcnt lgkmcnt(0)\n\ts_barrier" ::: "memory");
}
// Bounded acquire-poll on a device-scope flag (RMW -> always coherent).
__device__ __forceinline__ void wait_flag_ge(int* f, int need) {
    for (int i = 0; i < 2000000; ++i) {
        int v = __hip_atomic_fetch_add(f, 0, __ATOMIC_ACQUIRE,
                                       __HIP_MEMORY_SCOPE_AGENT);
        if (v >= need) return;
        __builtin_amdgcn_s_sleep(4);
    }
}
// Truncation-based hi/lo bf16 split of two floats, packed into 2 u32
// (lo16 = elem a, hi16 = elem b).
__device__ __forceinline__ void split2(float a, float b,
                                       unsigned& hi, unsigned& lo) {
    unsigned ua = __float_as_uint(a), ub = __float_as_uint(b);
    hi = (ua >> 16) | (ub & 0xFFFF0000u);
    float ra = a - __uint_as_float(ua & 0xFFFF0000u);
    float rb = b - __uint_as_float(ub & 0xFFFF0000u);
    lo = (__float_as_uint(ra) >> 16) | (__float_as_uint(rb) & 0xFFFF0000u);
}

// MFMA 16x16x32 layouts: A/B: m(n)=lane&15, k=(lane>>4)*8+j ; C/D: col=lane&15,
// row=(lane>>4)*4+r.

__global__ __launch_bounds__(512, 1) void fused_lstm_kernel(
    const float* __restrict__ x,
    const float* __restrict__ Wih0, const float* __restrict__ Whh0,
    const float* __restrict__ bih0, const float* __restrict__ bhh0,
    const float* __restrict__ Wih1, const float* __restrict__ Whh1,
    const float* __restrict__ bih1, const float* __restrict__ bhh1,
    _Float16* __restrict__ h1c, float* __restrict__ hs, int* __restrict__ flags)
{
    const int tid = threadIdx.x;
    const int w = tid >> 6;
    const int l = tid & 63;
    const int lane16 = l & 15;
    const int quad = l >> 4;
    const int jh = 16 * w + lane16;

    __shared__ __align__(16) _Float16 hbuf[2][16 * 136];     // 8704 B
    __shared__ __align__(16) short    pool[3][2][16 * 72];   // 13824 B

    if (blockIdx.x < 64) {
        // ================= LAYER 0 (producer) =================
        const int tile = blockIdx.x;
        const long b0 = (long)tile * 16;
        int* flagp = &flags[tile];

        v8h bh[4][4];                 // Whh0 fp16 B-frags
        v8s bxh[4][2], bxl[4][2];     // Wih0 split-bf16 B-frags
        float bias[4];
        float c[4] = {0.f, 0.f, 0.f, 0.f};

#pragma unroll
        for (int g = 0; g < 4; ++g) {
            const int col = g * 128 + jh;
            bias[g] = bih0[col] + bhh0[col];
#pragma unroll
            for (int q = 0; q < 4; ++q) {
                const float* p = &Whh0[(long)col * HH + q * 32 + quad * 8];
                float4 u0 = *(const float4*)p;
                float4 u1 = *(const float4*)(p + 4);
                v8h t;
                t[0]=(_Float16)u0.x; t[1]=(_Float16)u0.y; t[2]=(_Float16)u0.z; t[3]=(_Float16)u0.w;
                t[4]=(_Float16)u1.x; t[5]=(_Float16)u1.y; t[6]=(_Float16)u1.z; t[7]=(_Float16)u1.w;
                bh[g][q] = t;
            }
#pragma unroll
            for (int q = 0; q < 2; ++q) {
                const float* p = &Wih0[(long)col * FF + q * 32 + quad * 8];
                float4 u0 = *(const float4*)p;
                float4 u1 = *(const float4*)(p + 4);
                float vv[8] = {u0.x,u0.y,u0.z,u0.w,u1.x,u1.y,u1.z,u1.w};
                v8s hi, lo;
#pragma unroll
                for (int e = 0; e < 8; ++e) {
                    short hbits = bf16r(vv[e]);
                    hi[e] = hbits;
                    lo[e] = bf16r(vv[e] - bf16tof(hbits));
                }
                bxh[g][q] = hi; bxl[g][q] = lo;
            }
        }

        for (int i = tid; i < 16 * 136; i += 512) hbuf[0][i] = (_Float16)0.0f;

        // ---- cooperative x staging: thread owns 2 floats of the 16x64 tile
        const int xr_row = tid >> 5;          // 0..15 (batch row within tile)
        const int xr_col = (tid & 31) * 2;    // 0..62, even
        const float* xp = &x[(b0 + xr_row) * TT * FF + xr_col];
        float2 x0v  = *(const float2*)xp;             // x(0)
        float2 x1v  = *(const float2*)(xp + FF);      // x(1)
        float2 xreg = *(const float2*)(xp + 2 * FF);  // x(2)
        xp += 3 * FF;                                 // -> x(3)
        {
            unsigned hi, lo; split2(x0v.x, x0v.y, hi, lo);
            *(unsigned*)&pool[0][0][xr_row * 72 + xr_col] = hi;
            *(unsigned*)&pool[0][1][xr_row * 72 + xr_col] = lo;
        }
        __syncthreads();

        // xacc(0) = bias + Wih0*x(0), from slot 0
        v4f xacc[4];
        {
            v8s xh[2], xl[2];
#pragma unroll
            for (int q = 0; q < 2; ++q) {
                xh[q] = *(const v8s*)&pool[0][0][lane16 * 72 + q * 32 + quad * 8];
                xl[q] = *(const v8s*)&pool[0][1][lane16 * 72 + q * 32 + quad * 8];
            }
#pragma unroll
            for (int g = 0; g < 4; ++g) {
                v4f a = {bias[g], bias[g], bias[g], bias[g]};
                a = __builtin_amdgcn_mfma_f32_16x16x32_bf16(xh[0], bxh[g][0], a, 0, 0, 0);
                a = __builtin_amdgcn_mfma_f32_16x16x32_bf16(xh[0], bxl[g][0], a, 0, 0, 0);
                a = __builtin_amdgcn_mfma_f32_16x16x32_bf16(xl[0], bxh[g][0], a, 0, 0, 0);
                a = __builtin_amdgcn_mfma_f32_16x16x32_bf16(xh[1], bxh[g][1], a, 0, 0, 0);
                a = __builtin_amdgcn_mfma_f32_16x16x32_bf16(xh[1], bxl[g][1], a, 0, 0, 0);
                a = __builtin_amdgcn_mfma_f32_16x16x32_bf16(xl[1], bxh[g][1], a, 0, 0, 0);
                xacc[g] = a;
            }
        }
        {   // stage x(1) into slot 1
            unsigned hi, lo; split2(x1v.x, x1v.y, hi, lo);
            *(unsigned*)&pool[1][0][xr_row * 72 + xr_col] = hi;
            *(unsigned*)&pool[1][1][xr_row * 72 + xr_col] = lo;
        }
        light_barrier();

        _Float16* h1p = h1c + (b0 + quad * 4) * HH + jh;   // [t][B][H]
        int r1 = 1, r2 = 2;   // r1: slot holding x(t+1); r2: slot to write x(t+2)

        for (int t = 0; t < TT; ++t) {
            const int cur = t & 1, nxt = cur ^ 1;

            // ---- critical path: recurrence MFMAs ----
            v8h ah[4];
#pragma unroll
            for (int q = 0; q < 4; ++q)
                ah[q] = *(const v8h*)&hbuf[cur][lane16 * 136 + q * 32 + quad * 8];

            v4f g0 = xacc[0], g1 = xacc[1], g2 = xacc[2], g3 = xacc[3];
#pragma unroll
            for (int q = 0; q < 4; ++q) {
                g0 = __builtin_amdgcn_mfma_f32_16x16x32_f16(ah[q], bh[0][q], g0, 0, 0, 0);
                g1 = __builtin_amdgcn_mfma_f32_16x16x32_f16(ah[q], bh[1][q], g1, 0, 0, 0);
                g2 = __builtin_amdgcn_mfma_f32_16x16x32_f16(ah[q], bh[2][q], g2, 0, 0, 0);
                g3 = __builtin_amdgcn_mfma_f32_16x16x32_f16(ah[q], bh[3][q], g3, 0, 0, 0);
            }

#pragma unroll
            for (int r = 0; r < 4; ++r) {
                float ig = sigmoidf_(g0[r]);
                float fg = sigmoidf_(g1[r]);
                float gg = tanhf_(g2[r]);
                float og = sigmoidf_(g3[r]);
                c[r] = fmaf(fg, c[r], ig * gg);
                float h = og * tanhf_(c[r]);
                const int m = quad * 4 + r;
                const _Float16 hh = (_Float16)h;
                h1p[r * HH] = hh;
                hbuf[nxt][m * 136 + jh] = hh;
            }
            h1p += (long)BB * HH;

            // ---- off-path: xacc(t+1) = bias + Wih0*x(t+1) from slot r1 ----
            {
                v8s xh[2], xl[2];
#pragma unroll
                for (int q = 0; q < 2; ++q) {
                    xh[q] = *(const v8s*)&pool[r1][0][lane16 * 72 + q * 32 + quad * 8];
                    xl[q] = *(const v8s*)&pool[r1][1][lane16 * 72 + q * 32 + quad * 8];
                }
#pragma unroll
                for (int g = 0; g < 4; ++g) {
                    v4f a = {bias[g], bias[g], bias[g], bias[g]};
                    a = __builtin_amdgcn_mfma_f32_16x16x32_bf16(xh[0], bxh[g][0], a, 0, 0, 0);
                    a = __builtin_amdgcn_mfma_f32_16x16x32_bf16(xh[0], bxl[g][0], a, 0, 0, 0);
                    a = __builtin_amdgcn_mfma_f32_16x16x32_bf16(xl[0], bxh[g][0], a, 0, 0, 0);
                    a = __builtin_amdgcn_mfma_f32_16x16x32_bf16(xh[1], bxh[g][1], a, 0, 0, 0);
                    a = __builtin_amdgcn_mfma_f32_16x16x32_bf16(xh[1], bxl[g][1], a, 0, 0, 0);
                    a = __builtin_amdgcn_mfma_f32_16x16x32_bf16(xl[1], bxh[g][1], a, 0, 0, 0);
                    xacc[g] = a;
                }
            }

            // ---- stage x(t+2) into slot r2; prefetch x(t+3) ----
            {
                unsigned hi, lo; split2(xreg.x, xreg.y, hi, lo);
                *(unsigned*)&pool[r2][0][xr_row * 72 + xr_col] = hi;
                *(unsigned*)&pool[r2][1][xr_row * 72 + xr_col] = lo;
            }
            xreg = *(const float2*)xp;
            if (t < TT - 4) xp += FF;

            {   // rotate slots: new r1 = r2, new r2 = the freed slot
                const int r0 = 3 - r1 - r2;
                r1 = r2; r2 = r0;
            }

            if ((t & 7) == 7) {
                __syncthreads();  // drains every wave's h1c stores (vmcnt 0)
                if (tid == 0)
                    __hip_atomic_store(flagp, t + 1, __ATOMIC_RELEASE,
                                       __HIP_MEMORY_SCOPE_AGENT);
            } else {
                light_barrier();
            }
        }
    } else {
        // ================= LAYER 1 (consumer) =================
        const int tile = blockIdx.x - 64;
        const long b0 = (long)tile * 16;
        int* flagp = &flags[tile];

        v8h bi[4][4], bh[4][4];
        float bias[4];
        float c[4] = {0.f, 0.f, 0.f, 0.f};

#pragma unroll
        for (int g = 0; g < 4; ++g) {
            const int col = g * 128 + jh;
            bias[g] = bih1[col] + bhh1[col];
#pragma unroll
            for (int q = 0; q < 4; ++q) {
                const float* pi = &Wih1[(long)col * HH + q * 32 + quad * 8];
                float4 u0 = *(const float4*)pi;
                float4 u1 = *(const float4*)(pi + 4);
                v8h t;
                t[0]=(_Float16)u0.x; t[1]=(_Float16)u0.y; t[2]=(_Float16)u0.z; t[3]=(_Float16)u0.w;
                t[4]=(_Float16)u1.x; t[5]=(_Float16)u1.y; t[6]=(_Float16)u1.z; t[7]=(_Float16)u1.w;
                bi[g][q] = t;
                const float* ph = &Whh1[(long)col * HH + q * 32 + quad * 8];
                float4 v0 = *(const float4*)ph;
                float4 v1 = *(const float4*)(ph + 4);
                v8h s;
                s[0]=(_Float16)v0.x; s[1]=(_Float16)v0.y; s[2]=(_Float16)v0.z; s[3]=(_Float16)v0.w;
                s[4]=(_Float16)v1.x; s[5]=(_Float16)v1.y; s[6]=(_Float16)v1.z; s[7]=(_Float16)v1.w;
                bh[g][q] = s;
            }
        }

        for (int i = tid; i < 16 * 136; i += 512) hbuf[0][i] = (_Float16)0.0f;

        _Float16* sb = (_Float16*)&pool[0][0][0];   // 3 slots, stride 2304 halves
        const int SBS = 2304;

        const int hr_row = tid >> 5;          // 0..15
        const int hr_col = (tid & 31) * 4;    // 0..124, multiple of 4

        // wait for h1[0..15] before the t=0 staging (covers prefetch window)
        if (tid == 0) wait_flag_ge(flagp, 16);
        __syncthreads();

        const _Float16* hp = h1c + (b0 + hr_row) * HH + hr_col;  // [t][B][H], t=0
        uint2 h0v  = *(const uint2*)hp;                    // h1(0)
        uint2 h1v  = *(const uint2*)(hp + (long)BB * HH);  // h1(1)
        uint2 hreg = *(const uint2*)(hp + 2L * BB * HH);   // h1(2)
        hp += 3L * BB * HH;                                // -> h1(3)
        *(uint2*)&sb[0 * SBS + hr_row * 136 + hr_col] = h0v;
        __syncthreads();

        // a1acc(0) = bias + Wih1*h1(0), from slot 0
        v4f a1acc[4];
        {
            v8h a1[4];
#pragma unroll
            for (int q = 0; q < 4; ++q)
                a1[q] = *(const v8h*)&sb[0 * SBS + lane16 * 136 + q * 32 + quad * 8];
#pragma unroll
            for (int g = 0; g < 4; ++g) {
                v4f a = {bias[g], bias[g], bias[g], bias[g]};
#pragma unroll
                for (int q = 0; q < 4; ++q)
                    a = __builtin_amdgcn_mfma_f32_16x16x32_f16(a1[q], bi[g][q], a, 0, 0, 0);
                a1acc[g] = a;
            }
        }
        *(uint2*)&sb[1 * SBS + hr_row * 136 + hr_col] = h1v;   // slot1 = h1(1)
        light_barrier();

        int r1 = 1, r2 = 2;
        for (int t = 0; t < TT; ++t) {
            if ((t & 7) == 0 && t > 0) {
                if (tid == 0) wait_flag_ge(flagp, (t + 16 < TT) ? t + 16 : TT);
                light_barrier();
            }
            const int cur = t & 1, nxt = cur ^ 1;

            // ---- critical path: recurrence MFMAs ----
            v8h a2[4];
#pragma unroll
            for (int q = 0; q < 4; ++q)
                a2[q] = *(const v8h*)&hbuf[cur][lane16 * 136 + q * 32 + quad * 8];

            v4f g0 = a1acc[0], g1 = a1acc[1], g2 = a1acc[2], g3 = a1acc[3];
#pragma unroll
            for (int q = 0; q < 4; ++q) {
                g0 = __builtin_amdgcn_mfma_f32_16x16x32_f16(a2[q], bh[0][q], g0, 0, 0, 0);
                g1 = __builtin_amdgcn_mfma_f32_16x16x32_f16(a2[q], bh[1][q], g1, 0, 0, 0);
                g2 = __builtin_amdgcn_mfma_f32_16x16x32_f16(a2[q], bh[2][q], g2, 0, 0, 0);
                g3 = __builtin_amdgcn_mfma_f32_16x16x32_f16(a2[q], bh[3][q], g3, 0, 0, 0);
            }

#pragma unroll
            for (int r = 0; r < 4; ++r) {
                float ig = sigmoidf_(g0[r]);
                float fg = sigmoidf_(g1[r]);
                float gg = tanhf_(g2[r]);
                float og = sigmoidf_(g3[r]);
                c[r] = fmaf(fg, c[r], ig * gg);
                float h = og * tanhf_(c[r]);
                const int m = quad * 4 + r;
                hbuf[nxt][m * 136 + jh] = (_Float16)h;
                if (t == TT - 1) hs[(b0 + m) * HH + jh] = h;
            }

            // ---- off-path: a1acc(t+1) = bias + Wih1*h1(t+1) from slot r1 ----
            {
                v8h a1[4];
#pragma unroll
                for (int q = 0; q < 4; ++q)
                    a1[q] = *(const v8h*)&sb[r1 * SBS + lane16 * 136 + q * 32 + quad * 8];
#pragma unroll
                for (int g = 0; g < 4; ++g) {
                    v4f a = {bias[g], bias[g], bias[g], bias[g]};
#pragma unroll
                    for (int q = 0; q < 4; ++q)
                        a = __builtin_amdgcn_mfma_f32_16x16x32_f16(a1[q], bi[g][q], a, 0, 0, 0);
                    a1acc[g] = a;
                }
            }

            // ---- stage h1(t+2) into slot r2; prefetch h1(t+3) ----
            *(uint2*)&sb[r2 * SBS + hr_row * 136 + hr_col] = hreg;
            hreg = *(const uint2*)hp;
            if (t < TT - 4) hp += (long)BB * HH;

            {
                const int r0 = 3 - r1 - r2;
                r1 = r2; r2 = r0;
            }

            light_barrier();
        }
    }
}

// ---------------- FC head: out = relu(h @ fc1^T + b1) @ fc2^T + b2 ----------
__global__ __launch_bounds__(64) void head_kernel(
    const float* __restrict__ h, const float* __restrict__ w1,
    const float* __restrict__ b1, const float* __restrict__ w2,
    const float* __restrict__ b2, float* __restrict__ out)
{
    const int b = blockIdx.x;
    const int n = threadIdx.x;
    float acc = b1[n];
#pragma unroll
    for (int k = 0; k < HH; ++k)
        acc = fmaf(w1[n * HH + k], h[b * HH + k], acc);
    float v = fmaxf(acc, 0.0f) * w2[n];
#pragma unroll
    for (int off = 32; off > 0; off >>= 1)
        v += __shfl_down(v, off);
    if (n == 0) out[b] = v + b2[0];
}

extern "C" void kernel_launch(void* const* d_in, const int* in_sizes, int n_in,
                              void* d_out, int out_size, void* d_ws, size_t ws_size,
                              hipStream_t stream)
{
    const float* x    = (const float*)d_in[0];
    const float* Wih0 = (const float*)d_in[1];
    const float* Whh0 = (const float*)d_in[2];
    const float* bih0 = (const float*)d_in[3];
    const float* bhh0 = (const float*)d_in[4];
    const float* Wih1 = (const float*)d_in[5];
    const float* Whh1 = (const float*)d_in[6];
    const float* bih1 = (const float*)d_in[7];
    const float* bhh1 = (const float*)d_in[8];
    const float* w1   = (const float*)d_in[9];
    const float* b1   = (const float*)d_in[10];
    const float* w2   = (const float*)d_in[11];
    const float* b2   = (const float*)d_in[12];
    float* out = (float*)d_out;

    char* ws = (char*)d_ws;
    _Float16* h1c = (_Float16*)ws;                              // 134 MB, [t][B][H]
    float* hs  = (float*)(ws + (size_t)BB * TT * HH * sizeof(_Float16));
    int* flags = (int*)(ws + (size_t)BB * TT * HH * sizeof(_Float16)
                           + (size_t)BB * HH * sizeof(float));

    hipMemsetAsync(flags, 0, 64 * sizeof(int), stream);

    fused_lstm_kernel<<<128, 512, 0, stream>>>(
        x, Wih0, Whh0, bih0, bhh0, Wih1, Whh1, bih1, bhh1, h1c, hs, flags);
    head_kernel<<<BB, 64, 0, stream>>>(hs, w1, b1, w2, b2, out);
}